// Round 4
// baseline (139.814 us; speedup 1.0000x reference)
//
#include <hip/hip_runtime.h>

#define N_NODES 50000
#define N_EDGES 800000
#define D 96
#define D4 (D / 4)        // 24 float4 per row

#define RL 12             // bf16 row = 96*2B = 12 uint4 per node row
#define HPAD 13           // LDS h-row stride in uint4 (kills bank conflicts)

// ---- counting-sort geometry ----
#define NB 196            // buckets of 256 nodes (ceil(50000/256))
#define ECAP 5120         // per-bucket dst-edge capacity (mean 4081, +16 sigma)
#define SCAP 5120         // per-bucket src-entry capacity (same stats)
#define HCCAP 3072        // per HALF-bucket (128 nodes) padded-CSR cap (mean ~2490, +13 sigma)
#define PA_BLOCKS 400
#define PA_CHUNK 2000     // 400 * 2000 = 800000 exact; ~1.6 blocks/CU
#define SB_BLOCKS 392     // 2 half-blocks per bucket
#define WPREP_TB 5        // tail blocks of sortB grid for WT prep (5*1024 >= 4608)

typedef __attribute__((ext_vector_type(8))) short short8;
typedef __attribute__((ext_vector_type(4))) float floatx4;

__device__ __forceinline__ short8 as_short8(uint4 u) { return *(short8*)&u; }

// bf16 RTNE pack: a -> low 16, b -> high 16.
__device__ __forceinline__ unsigned bf16pack(float a, float b) {
    unsigned ua = __float_as_uint(a);
    unsigned ub = __float_as_uint(b);
    ua = (ua + 0x7FFFu + ((ua >> 16) & 1u)) >> 16;       // RTNE
    ub = (ub + 0x7FFFu + ((ub >> 16) & 1u)) & 0xFFFF0000u;
    return ua | ub;
}

// Stage 1a: dual-key bucket partition (verified in R3; only grid params changed
// 256x3125 -> 400x2000 for ~1.6 blocks/CU phase overlap). Edges go to
// dst-buckets (ebuf, (dst<<16)|src) AND src values to src-buckets (sbuf, u16)
// via one LDS counting sort with a fused 512-wide dual scan. No global data
// atomics.
__global__ void __launch_bounds__(1024) sortA_kernel(
        const int* __restrict__ src, const int* __restrict__ dst,
        unsigned* __restrict__ gcur,       // [2*NB]: dst cursors | src cursors
        unsigned* __restrict__ ebuf, unsigned short* __restrict__ sbuf) {
    __shared__ unsigned raw[PA_CHUNK];          // 8 KB
    __shared__ unsigned ord[PA_CHUNK];          // 8 KB
    __shared__ unsigned short sord[PA_CHUNK];   // 4 KB
    __shared__ unsigned hist[512];   // [0..255] dst-buckets, [256..511] src-buckets
    __shared__ unsigned sc[512], lstart[512], cur[512], gbase[512];
    int t = threadIdx.x;
    int e0 = blockIdx.x * PA_CHUNK;
    if (t < 512) hist[t] = 0;
    __syncthreads();
    for (int i = t; i < PA_CHUNK; i += 1024) {
        int s = src[e0 + i];
        int d = dst[e0 + i];
        raw[i] = ((unsigned)d << 16) | (unsigned)s;
        atomicAdd(&hist[d >> 8], 1u);
        atomicAdd(&hist[256 + (s >> 8)], 1u);
    }
    __syncthreads();
    if (t < 512) sc[t] = hist[t];
    __syncthreads();
    for (int o = 1; o < 256; o <<= 1) {      // two Hillis-Steele scans, fused
        unsigned v = 0;
        if (t < 512 && (t & 255) >= o) v = sc[t - o];
        __syncthreads();
        if (t < 512 && (t & 255) >= o) sc[t] += v;
        __syncthreads();
    }
    if (t < 512) {
        unsigned ls = sc[t] - hist[t];       // exclusive
        lstart[t] = ls;
        cur[t] = ls;
        if ((t & 255) < NB)
            gbase[t] = atomicAdd(&gcur[(t >> 8) * NB + (t & 255)], hist[t]);
    }
    __syncthreads();
    for (int i = t; i < PA_CHUNK; i += 1024) {   // LDS scatter into bucket order
        unsigned r = raw[i];
        unsigned p = atomicAdd(&cur[r >> 24], 1u);        // dst bucket
        ord[p] = r;
        unsigned s = r & 0xFFFFu;
        unsigned q = atomicAdd(&cur[256 + (s >> 8)], 1u); // src bucket
        sord[q] = (unsigned short)s;
    }
    __syncthreads();
    for (int i = t; i < PA_CHUNK; i += 1024) {   // coalesced-run copy-out
        unsigned r = ord[i];
        unsigned bd = r >> 24;
        unsigned pos = gbase[bd] + ((unsigned)i - lstart[bd]);
        if (pos < ECAP) ebuf[bd * ECAP + pos] = r;
        unsigned s = sord[i];
        unsigned bs = 256 + (s >> 8);
        unsigned pos2 = gbase[bs] + ((unsigned)i - lstart[bs]);
        if (pos2 < SCAP) sbuf[(size_t)(bs - 256) * SCAP + pos2] = (unsigned short)s;
    }
}

// Stage 1b (restructured): 392 half-bucket blocks (128 owned nodes each,
// ~1.5 blocks/CU) + 5 WT-prep tail blocks. Per block: count owned dst/src
// (-> deg_in + in-LDS deg_out), 2-barrier shfl scan -> off, fused sfeat
// production for owned nodes (old conv kernel), then LDS CSR scatter +
// coalesced copy-out. No eb[] staging (bucket region re-read from hot L2),
// LDS ~8 KB so resident blocks overlap phases.
__global__ void __launch_bounds__(1024) sortB_kernel(
        const unsigned* __restrict__ gcur, const unsigned* __restrict__ ebuf,
        const unsigned short* __restrict__ sbuf,
        const float4* __restrict__ feat4, const float* __restrict__ W,
        unsigned* __restrict__ WT32,
        int* __restrict__ deg_in, int* __restrict__ off,
        unsigned short* __restrict__ csr, uint4* __restrict__ sfeat) {
    int blk = blockIdx.x;
    if (blk >= SB_BLOCKS) {   // WT prep tail
        int t = (blk - SB_BLOCKS) * 1024 + threadIdx.x;
        if (t >= D * (D / 2)) return;
        int n = t / (D / 2);
        int j = t - n * (D / 2);
        float w0 = W[(2 * j) * D + n];
        float w1 = W[(2 * j + 1) * D + n];
        WT32[n * (D / 2) + j] = bf16pack(w0, w1);
        return;
    }
    __shared__ unsigned short csr_l[HCCAP];     // 6 KB
    __shared__ unsigned dcount[128], dcur[128], scount[128];
    __shared__ unsigned wtot, tot_s;
    int b = blk >> 1;          // bucket 0..195
    unsigned half = (unsigned)(blk & 1);
    int t = threadIdx.x;
    unsigned cntd = gcur[b];      if (cntd > ECAP) cntd = ECAP;
    unsigned cnts = gcur[NB + b]; if (cnts > SCAP) cnts = SCAP;
    if (t < 128) { dcount[t] = 0; scount[t] = 0; }
    __syncthreads();
    const unsigned* __restrict__ sg = ebuf + (size_t)b * ECAP;
    for (int i = t; i < (int)cntd; i += 1024) {
        unsigned loc = (sg[i] >> 16) & 255u;
        if ((loc >> 7) == half) atomicAdd(&dcount[loc & 127u], 1u);
    }
    const unsigned short* __restrict__ ss = sbuf + (size_t)b * SCAP;
    for (int i = t; i < (int)cnts; i += 1024) {
        unsigned loc = ss[i] & 255u;
        if ((loc >> 7) == half) atomicAdd(&scount[loc & 127u], 1u);
    }
    __syncthreads();
    // ---- 2-barrier shfl scan of 8-padded sizes (threads 0..127 = waves 0,1) ----
    unsigned pad = 0, incl = 0;
    if (t < 128) {
        pad = (dcount[t] + 7u) & ~7u;
        incl = pad;
        int lane = t & 63;
#pragma unroll
        for (int st = 1; st < 64; st <<= 1) {
            unsigned u = __shfl_up(incl, st, 64);
            if (lane >= st) incl += u;
        }
        if (t == 63) wtot = incl;
    }
    __syncthreads();
    if (t < 128) {
        if (t >= 64) incl += wtot;
        unsigned ex = incl - pad;               // exclusive padded
        dcur[t] = ex;
        if (t == 127) tot_s = incl;
        int n = b * 256 + (int)(half << 7) + t;
        if (n < N_NODES) {
            deg_in[n] = (int)dcount[t];
            off[n] = blk * HCCAP + (int)ex;     // == (n>>7)*HCCAP + ex
        }
    }
    __syncthreads();
    // ---- CSR scatter (owned nodes only; sg re-read from L2) ----
    for (int i = t; i < (int)cntd; i += 1024) {
        unsigned r = sg[i];
        unsigned loc = (r >> 16) & 255u;
        if ((loc >> 7) == half) {
            unsigned p = atomicAdd(&dcur[loc & 127u], 1u);
            if (p < HCCAP) csr_l[p] = (unsigned short)(r & 0xFFFFu);
        }
    }
    __syncthreads();
    unsigned tot = tot_s;
    if (tot > HCCAP) tot = HCCAP;
    unsigned* __restrict__ og = (unsigned*)(csr + (size_t)blk * HCCAP);
    const unsigned* __restrict__ cl = (const unsigned*)csr_l;
    for (int i = t; i < (int)(tot >> 1); i += 1024) og[i] = cl[i];
    // ---- fused conv: sfeat rows for the 128 owned nodes ----
    int base_n = b * 256 + (int)(half << 7);
    for (int r = t; r < 128 * RL; r += 1024) {
        int nl = r / RL;
        int lane = r - nl * RL;
        int n = base_n + nl;
        if (n < N_NODES) {
            float c = rsqrtf(fmaxf((float)scount[nl], 1.0f));
            float4 a = feat4[(size_t)n * D4 + lane * 2];
            float4 bb = feat4[(size_t)n * D4 + lane * 2 + 1];
            uint4 o;
            o.x = bf16pack(a.x * c, a.y * c);
            o.y = bf16pack(a.z * c, a.w * c);
            o.z = bf16pack(bb.x * c, bb.y * c);
            o.w = bf16pack(bb.z * c, bb.w * c);
            sfeat[(size_t)n * RL + lane] = o;
        }
    }
}

// Stage 2 (fused gather+MFMA): UNCHANGED from R3 (verified). One block = one
// 16-row tile. Gather: 192 threads (16 nodes x 12 lanes), 16-deep row
// prefetch. MFMA: 3 waves x 2 col-tiles, mfma_f32_16x16x32_bf16, bias, fp32.
// Layouts (m89/m91-verified): A[m=lane&15][k=quad*8+j]; B[k=quad*8+j][n=lane&15];
// D col=lane&15, row=quad*4+reg.
__global__ void __launch_bounds__(192) gather_mm_kernel(
        const float4* __restrict__ feat4, const uint4* __restrict__ sfeat,
        const int* __restrict__ deg_in, const int* __restrict__ off,
        const unsigned short* __restrict__ csr, const uint4* __restrict__ wt4,
        const float* __restrict__ bias, float* __restrict__ out) {
    __shared__ uint4 sh[16 * HPAD];   // 3.25 KB
    int tid = threadIdx.x;
    {   // ---- gather phase ----
        int g = tid / RL;            // node 0..15
        int lane = tid - g * RL;     // uint4 index 0..11 (8 bf16)
        int n = blockIdx.x * 16 + g; // 3125*16 = 50000 exact
        int deg = deg_in[n];
        uint4* __restrict__ hout = &sh[g * HPAD + lane];
        if (deg == 0) {
            float4 a = feat4[n * D4 + lane * 2];
            float4 b = feat4[n * D4 + lane * 2 + 1];
            uint4 o;
            o.x = bf16pack(a.x, a.y);
            o.y = bf16pack(a.z, a.w);
            o.z = bf16pack(b.x, b.y);
            o.w = bf16pack(b.z, b.w);
            *hout = o;
        } else {
            const unsigned short* __restrict__ bk = csr + off[n];
            const uint4* __restrict__ sf = sfeat + lane;
            float acc[8] = {};
#define ACC8(v)  { \
        acc[0] += __uint_as_float((v).x << 16); \
        acc[1] += __uint_as_float((v).x & 0xFFFF0000u); \
        acc[2] += __uint_as_float((v).y << 16); \
        acc[3] += __uint_as_float((v).y & 0xFFFF0000u); \
        acc[4] += __uint_as_float((v).z << 16); \
        acc[5] += __uint_as_float((v).z & 0xFFFF0000u); \
        acc[6] += __uint_as_float((v).w << 16); \
        acc[7] += __uint_as_float((v).w & 0xFFFF0000u); }
            int i = 0;
            int full16 = deg & ~15;
            for (; i < full16; i += 16) {
                uint4 ia = *(const uint4*)(bk + i);       // 8 u16 indices
                uint4 ib = *(const uint4*)(bk + i + 8);   // 8 more
                unsigned s0 = ia.x & 0xFFFFu, s1 = ia.x >> 16;
                unsigned s2 = ia.y & 0xFFFFu, s3 = ia.y >> 16;
                unsigned s4 = ia.z & 0xFFFFu, s5 = ia.z >> 16;
                unsigned s6 = ia.w & 0xFFFFu, s7 = ia.w >> 16;
                unsigned s8 = ib.x & 0xFFFFu, s9 = ib.x >> 16;
                unsigned sa = ib.y & 0xFFFFu, sb = ib.y >> 16;
                unsigned sx = ib.z & 0xFFFFu, sd = ib.z >> 16;
                unsigned se = ib.w & 0xFFFFu, sfi = ib.w >> 16;
                uint4 v0 = sf[(size_t)s0 * RL];
                uint4 v1 = sf[(size_t)s1 * RL];
                uint4 v2 = sf[(size_t)s2 * RL];
                uint4 v3 = sf[(size_t)s3 * RL];
                uint4 v4 = sf[(size_t)s4 * RL];
                uint4 v5 = sf[(size_t)s5 * RL];
                uint4 v6 = sf[(size_t)s6 * RL];
                uint4 v7 = sf[(size_t)s7 * RL];
                uint4 v8 = sf[(size_t)s8 * RL];
                uint4 v9 = sf[(size_t)s9 * RL];
                uint4 va = sf[(size_t)sa * RL];
                uint4 vb = sf[(size_t)sb * RL];
                uint4 vc = sf[(size_t)sx * RL];
                uint4 vd = sf[(size_t)sd * RL];
                uint4 ve = sf[(size_t)se * RL];
                uint4 vf = sf[(size_t)sfi * RL];
                ACC8(v0); ACC8(v1); ACC8(v2); ACC8(v3);
                ACC8(v4); ACC8(v5); ACC8(v6); ACC8(v7);
                ACC8(v8); ACC8(v9); ACC8(va); ACC8(vb);
                ACC8(vc); ACC8(vd); ACC8(ve); ACC8(vf);
            }
            int full8 = deg & ~7;
            for (; i < full8; i += 8) {
                uint4 idx = *(const uint4*)(bk + i);
                unsigned s0 = idx.x & 0xFFFFu, s1 = idx.x >> 16;
                unsigned s2 = idx.y & 0xFFFFu, s3 = idx.y >> 16;
                unsigned s4 = idx.z & 0xFFFFu, s5 = idx.z >> 16;
                unsigned s6 = idx.w & 0xFFFFu, s7 = idx.w >> 16;
                uint4 v0 = sf[(size_t)s0 * RL];
                uint4 v1 = sf[(size_t)s1 * RL];
                uint4 v2 = sf[(size_t)s2 * RL];
                uint4 v3 = sf[(size_t)s3 * RL];
                uint4 v4 = sf[(size_t)s4 * RL];
                uint4 v5 = sf[(size_t)s5 * RL];
                uint4 v6 = sf[(size_t)s6 * RL];
                uint4 v7 = sf[(size_t)s7 * RL];
                ACC8(v0); ACC8(v1); ACC8(v2); ACC8(v3);
                ACC8(v4); ACC8(v5); ACC8(v6); ACC8(v7);
            }
            for (; i < deg; ++i) {
                uint4 v = sf[(size_t)bk[i] * RL];
                ACC8(v);
            }
#undef ACC8
            float cj = rsqrtf((float)deg);
            uint4 o;
            o.x = bf16pack(acc[0] * cj, acc[1] * cj);
            o.y = bf16pack(acc[2] * cj, acc[3] * cj);
            o.z = bf16pack(acc[4] * cj, acc[5] * cj);
            o.w = bf16pack(acc[6] * cj, acc[7] * cj);
            *hout = o;
        }
    }
    __syncthreads();
    // ---- MFMA phase ----
    int wave = tid >> 6;
    int lane = tid & 63;
    int m = lane & 15, quad = lane >> 4;
    short8 a0 = as_short8(sh[m * HPAD + quad]);       // k = 0..31
    short8 a1 = as_short8(sh[m * HPAD + 4 + quad]);   // k = 32..63
    short8 a2 = as_short8(sh[m * HPAD + 8 + quad]);   // k = 64..95
    int row0 = blockIdx.x * 16;
    int r_out0 = row0 + quad * 4;
#pragma unroll
    for (int ct = wave * 2; ct < wave * 2 + 2; ++ct) {
        int n = ct * 16 + m;
        int wb = n * RL + quad;
        short8 b0 = as_short8(wt4[wb]);
        short8 b1 = as_short8(wt4[wb + 4]);
        short8 b2 = as_short8(wt4[wb + 8]);
        floatx4 c = {0.f, 0.f, 0.f, 0.f};
        c = __builtin_amdgcn_mfma_f32_16x16x32_bf16(a0, b0, c, 0, 0, 0);
        c = __builtin_amdgcn_mfma_f32_16x16x32_bf16(a1, b1, c, 0, 0, 0);
        c = __builtin_amdgcn_mfma_f32_16x16x32_bf16(a2, b2, c, 0, 0, 0);
        float bs = bias[n];
#pragma unroll
        for (int r = 0; r < 4; ++r)
            out[(size_t)(r_out0 + r) * D + n] = c[r] + bs;
    }
}

extern "C" void kernel_launch(void* const* d_in, const int* in_sizes, int n_in,
                              void* d_out, int out_size, void* d_ws, size_t ws_size,
                              hipStream_t stream) {
    const float* feat = (const float*)d_in[0];
    const float* W    = (const float*)d_in[1];
    const float* bias = (const float*)d_in[2];
    const int*   src  = (const int*)d_in[3];
    const int*   dst  = (const int*)d_in[4];

    // ws layout (~18.8 MB; every byte rewritten each call or never read):
    //   gcur[2*NB] | deg_in[N] | off[N] |
    //   ebuf u32 [NB][ECAP] 4.0MB | sbuf u16 [NB][SCAP] 2.0MB |
    //   csr u16 [392][HCCAP] 2.4MB | sfeat 9.6MB | WT 18KB
    unsigned*       gcur    = (unsigned*)d_ws;
    int*            deg_in  = (int*)(gcur + 2 * NB);
    int*            off     = deg_in + N_NODES;
    unsigned*       ebuf    = (unsigned*)(off + N_NODES);
    unsigned short* sbuf    = (unsigned short*)(ebuf + (size_t)NB * ECAP);
    unsigned short* csr     = sbuf + (size_t)NB * SCAP;
    uint4*          sfeat   = (uint4*)(csr + (size_t)SB_BLOCKS * HCCAP);
    unsigned*       WT32    = (unsigned*)(sfeat + (size_t)N_NODES * RL);

    hipMemsetAsync(gcur, 0, 2 * NB * sizeof(unsigned), stream);
    sortA_kernel<<<PA_BLOCKS, 1024, 0, stream>>>(src, dst, gcur, ebuf, sbuf);
    sortB_kernel<<<SB_BLOCKS + WPREP_TB, 1024, 0, stream>>>(
        gcur, ebuf, sbuf, (const float4*)feat, W, WT32, deg_in, off, csr, sfeat);
    gather_mm_kernel<<<N_NODES / 16, 192, 0, stream>>>(
        (const float4*)feat, sfeat, deg_in, off, csr, (const uint4*)WT32,
        bias, (float*)d_out);
}